// Round 8
// baseline (370.888 us; speedup 1.0000x reference)
//
#include <hip/hip_runtime.h>
#include <hip/hip_bf16.h>
#include <math.h>

typedef __hip_bfloat16 bf16;
typedef __attribute__((ext_vector_type(8))) short short8;
typedef __attribute__((ext_vector_type(4))) float f32x4;

#define MFMA_BF16(a, b, c) __builtin_amdgcn_mfma_f32_16x16x32_bf16((a), (b), (c), 0, 0, 0)

// async global->LDS, 16B per lane (m97 pattern). LDS dest must be base + lane*16.
__device__ __forceinline__ void async_copy16(const bf16* g, bf16* l) {
  __builtin_amdgcn_global_load_lds(
      (const __attribute__((address_space(1))) void*)g,
      (__attribute__((address_space(3))) void*)l,
      16, 0, 0);
}

__device__ __forceinline__ unsigned short f2bf_bits(float f) {
  bf16 h = __float2bfloat16(f);
  return *reinterpret_cast<unsigned short*>(&h);
}

// ------------------------------------------- all fp32 -> bf16 in one launch
__global__ __launch_bounds__(256) void cvt_all(const float* __restrict__ x,
                                               const float* __restrict__ wq,
                                               const float* __restrict__ wk,
                                               const float* __restrict__ wv,
                                               const float* __restrict__ wp,
                                               bf16* __restrict__ xb, bf16* __restrict__ wqb,
                                               bf16* __restrict__ wkb, bf16* __restrict__ wvb,
                                               bf16* __restrict__ wpb) {
  const int bid = blockIdx.x;
  const float* in;
  bf16* out;
  int off;
  if (bid < 8192) {
    in = x; out = xb; off = bid;
  } else if (bid < 9216) {
    in = wq; out = wqb; off = bid - 8192;
  } else if (bid < 10240) {
    in = wk; out = wkb; off = bid - 9216;
  } else if (bid < 11264) {
    in = wv; out = wvb; off = bid - 10240;
  } else {
    in = wp; out = wpb; off = bid - 11264;
  }
  const int i = off * 256 + threadIdx.x;
  float4 v = reinterpret_cast<const float4*>(in)[i];
  ushort4 u;
  u.x = f2bf_bits(v.x);
  u.y = f2bf_bits(v.y);
  u.z = f2bf_bits(v.z);
  u.w = f2bf_bits(v.w);
  reinterpret_cast<ushort4*>(out)[i] = u;
}

// ------------------------------------------------- 128x128 GEMM core (C = A*W^T)
__device__ __forceinline__ void gemm_core(const bf16* __restrict__ A,
                                          const bf16* __restrict__ W,
                                          bf16* As, bf16* Bs, f32x4 (&acc)[4][4]) {
  const int tid = threadIdx.x;
  const int lane = tid & 63;
  const int l15 = lane & 15;
  const int quad = lane >> 4;
  const int wave = tid >> 6;
  const int wm = (wave >> 1) * 64;
  const int wn = (wave & 1) * 64;
  const int K = 1024;

  const f32x4 zero = {0.f, 0.f, 0.f, 0.f};
#pragma unroll
  for (int i = 0; i < 4; ++i)
#pragma unroll
    for (int j = 0; j < 4; ++j) acc[i][j] = zero;

  const int srow = tid >> 2;
  const int scol = (tid & 3) * 8;
  const bf16* ga = A + (size_t)(blockIdx.y * 128 + srow) * K + scol;
  const bf16* gb = W + (size_t)(blockIdx.x * 128 + srow) * K + scol;
  bf16* lA = As + tid * 8;
  bf16* lB = Bs + tid * 8;

  for (int kt = 0; kt < 32; ++kt) {
    const int k0 = kt * 32;
    async_copy16(ga + k0, lA);
    async_copy16(ga + k0 + 64 * K, lA + 2048);
    async_copy16(gb + k0, lB);
    async_copy16(gb + k0 + 64 * K, lB + 2048);
    __syncthreads();
    short8 afr[4], bfr[4];
#pragma unroll
    for (int i = 0; i < 4; ++i)
      afr[i] = *reinterpret_cast<const short8*>(As + (wm + i * 16 + l15) * 32 + quad * 8);
#pragma unroll
    for (int j = 0; j < 4; ++j)
      bfr[j] = *reinterpret_cast<const short8*>(Bs + (wn + j * 16 + l15) * 32 + quad * 8);
#pragma unroll
    for (int i = 0; i < 4; ++i)
#pragma unroll
      for (int j = 0; j < 4; ++j) acc[i][j] = MFMA_BF16(afr[i], bfr[j], acc[i][j]);
    __syncthreads();
  }
}

// fused q/k/v projection: grid (8, 64, 3). z==0 (Q) is pre-scaled by
// 0.125*log2(e) so attn's softmax uses raw exp2. z==2 (V) writes transposed
// into vt[bh][d][t].
__global__ __launch_bounds__(256) void gemm_qkv(const bf16* __restrict__ x,
                                                const bf16* __restrict__ wq,
                                                const bf16* __restrict__ wk,
                                                const bf16* __restrict__ wv,
                                                bf16* __restrict__ q, bf16* __restrict__ k,
                                                bf16* __restrict__ vt) {
  __shared__ __align__(16) bf16 As[128 * 32];
  __shared__ __align__(16) bf16 Bs[128 * 32];
  const bf16* W = (blockIdx.z == 0) ? wq : (blockIdx.z == 1) ? wk : wv;
  f32x4 acc[4][4];
  gemm_core(x, W, As, Bs, acc);
  const int tid = threadIdx.x, lane = tid & 63, l15 = lane & 15, quad = lane >> 4,
            wave = tid >> 6;
  const int wm = (wave >> 1) * 64, wn = (wave & 1) * 64;
  const int rb = blockIdx.y * 128 + wm + quad * 4;
  const int cb = blockIdx.x * 128 + wn + l15;
  if (blockIdx.z == 2) {
#pragma unroll
    for (int i = 0; i < 4; ++i)
#pragma unroll
      for (int j = 0; j < 4; ++j) {
        const int tg = rb + i * 16;
        const int col = cb + j * 16;
        const int b = tg >> 11, tl = tg & 2047;
        ushort4 pk;
        pk.x = f2bf_bits(acc[i][j][0]);
        pk.y = f2bf_bits(acc[i][j][1]);
        pk.z = f2bf_bits(acc[i][j][2]);
        pk.w = f2bf_bits(acc[i][j][3]);
        *reinterpret_cast<ushort4*>(&vt[((size_t)(b * 1024 + col)) * 2048 + tl]) = pk;
      }
  } else {
    const float qs = (blockIdx.z == 0) ? 0.18033688011112042f : 1.0f;  // 0.125*log2e
    bf16* C = (blockIdx.z == 0) ? q : k;
#pragma unroll
    for (int i = 0; i < 4; ++i)
#pragma unroll
      for (int j = 0; j < 4; ++j)
#pragma unroll
        for (int r = 0; r < 4; ++r)
          C[(size_t)(rb + i * 16 + r) * 1024 + cb + j * 16] =
              __float2bfloat16(acc[i][j][r] * qs);
  }
}

// output projection: grid (8, 64), fp32 out
__global__ __launch_bounds__(256) void gemm_proj(const bf16* __restrict__ y,
                                                 const bf16* __restrict__ wp,
                                                 float* __restrict__ outp) {
  __shared__ __align__(16) bf16 As[128 * 32];
  __shared__ __align__(16) bf16 Bs[128 * 32];
  f32x4 acc[4][4];
  gemm_core(y, wp, As, Bs, acc);
  const int tid = threadIdx.x, lane = tid & 63, l15 = lane & 15, quad = lane >> 4,
            wave = tid >> 6;
  const int wm = (wave >> 1) * 64, wn = (wave & 1) * 64;
  const int rb = blockIdx.y * 128 + wm + quad * 4;
  const int cb = blockIdx.x * 128 + wn + l15;
#pragma unroll
  for (int i = 0; i < 4; ++i)
#pragma unroll
    for (int j = 0; j < 4; ++j)
#pragma unroll
      for (int r = 0; r < 4; ++r)
        outp[(size_t)(rb + i * 16 + r) * 1024 + cb + j * 16] = acc[i][j][r];
}

// ----------------------------------------------------------- flash attention
// BARRIER-FREE: K and V^T MFMA fragments are 16B-contiguous per lane in
// global memory, so they load directly into registers (L1 broadcasts the
// identical addresses across the block's 4 waves) -- no LDS staging, no
// __syncthreads. Each wave runs its own k-range. LDS only holds the
// wave-local P C->A layout round-trip (lgkmcnt ordering only).
// Q comes pre-scaled by 0.125*log2e; grid (64 bh, 16 p); block p handles
// q-tiles p and 31-p; PV computed transposed (O^T = V^T * P^T).
__global__ __launch_bounds__(256) void attn(const bf16* __restrict__ qb,
                                            const bf16* __restrict__ kb,
                                            const bf16* __restrict__ vt,
                                            bf16* __restrict__ yb) {
  __shared__ __align__(16) bf16 Ps[4][32 * 40];
  const int tid = threadIdx.x;
  const int lane = tid & 63, l15 = lane & 15, quad = lane >> 4, wave = tid >> 6;
  const int p = blockIdx.y;
  const int bh = blockIdx.x;
  const int b = bh >> 4, h = bh & 15;
  const size_t rowbase = (size_t)b * 2048;
  const int cb = h * 64;

  const int tlo = p, thi = 31 - p;
  const int gq0[2] = {tlo * 64 + wave * 16, thi * 64 + wave * 16};

  short8 aq[2][2];
#pragma unroll
  for (int g = 0; g < 2; ++g) {
    const bf16* qp = qb + (rowbase + gq0[g] + l15) * 1024 + cb + quad * 8;
    aq[g][0] = *reinterpret_cast<const short8*>(qp);
    aq[g][1] = *reinterpret_cast<const short8*>(qp + 32);
  }

  short8 ones;
#pragma unroll
  for (int i = 0; i < 8; ++i) ones[i] = (short)0x3F80;  // bf16 1.0

  f32x4 o[2][4], l4[2];
  const f32x4 zero = {0.f, 0.f, 0.f, 0.f};
#pragma unroll
  for (int g = 0; g < 2; ++g) {
#pragma unroll
    for (int dt = 0; dt < 4; ++dt) o[g][dt] = zero;
    l4[g] = zero;
  }

  // per-lane fragment base addresses (16B-contiguous loads)
  const bf16* kfb = kb + (rowbase + l15) * 1024 + cb + quad * 8;  // + (k0g+j*16)*1024 + ks*32
  const bf16* vfb = vt + ((size_t)bh * 64 + l15) * 2048 + quad * 8;  // + dt*16*2048 + k0g
  bf16* Psw = &Ps[wave][0];

  const int last_k = (gq0[1] + 15) >> 5;  // this wave's final 32-key tile
  for (int kt = 0; kt <= last_k; ++kt) {
    const int k0g = kt * 32;
    // direct global->register fragment loads (VMEM pipe; L1-shared)
    short8 bk[2][2], av2[4];
#pragma unroll
    for (int j = 0; j < 2; ++j)
#pragma unroll
      for (int ks = 0; ks < 2; ++ks)
        bk[j][ks] = *reinterpret_cast<const short8*>(kfb + (size_t)(k0g + j * 16) * 1024 +
                                                     ks * 32);
#pragma unroll
    for (int dt = 0; dt < 4; ++dt)
      av2[dt] = *reinterpret_cast<const short8*>(vfb + (size_t)dt * 16 * 2048 + k0g);

#pragma unroll
    for (int g = 0; g < 2; ++g) {
      if (k0g > gq0[g] + 15) continue;
      f32x4 s[2];
#pragma unroll
      for (int j = 0; j < 2; ++j) {
        s[j] = MFMA_BF16(aq[g][0], bk[j][0], zero);
        s[j] = MFMA_BF16(aq[g][1], bk[j][1], s[j]);
      }
      if (k0g + 31 > gq0[g]) {  // diagonal-overlap tile: mask
#pragma unroll
        for (int j = 0; j < 2; ++j)
#pragma unroll
          for (int r = 0; r < 4; ++r) {
            float val = s[j][r];
            if ((k0g + j * 16 + l15) > (gq0[g] + quad * 4 + r)) val = -INFINITY;
            Psw[(g * 16 + quad * 4 + r) * 40 + j * 16 + l15] =
                __float2bfloat16(__builtin_amdgcn_exp2f(val));
          }
      } else {  // interior tile: no mask VALU
#pragma unroll
        for (int j = 0; j < 2; ++j)
#pragma unroll
          for (int r = 0; r < 4; ++r)
            Psw[(g * 16 + quad * 4 + r) * 40 + j * 16 + l15] =
                __float2bfloat16(__builtin_amdgcn_exp2f(s[j][r]));
      }
    }

    asm volatile("s_waitcnt lgkmcnt(0)" ::: "memory");  // wave-local P ordering

#pragma unroll
    for (int g = 0; g < 2; ++g) {
      if (k0g > gq0[g] + 15) continue;
      const short8 bp =
          *reinterpret_cast<const short8*>(Psw + (g * 16 + l15) * 40 + quad * 8);
#pragma unroll
      for (int dt = 0; dt < 4; ++dt) o[g][dt] = MFMA_BF16(av2[dt], bp, o[g][dt]);
      l4[g] = MFMA_BF16(ones, bp, l4[g]);
    }
  }

  // epilogue: lane holds q = gq0[g]+l15, d = dt*16 + quad*4 + r
#pragma unroll
  for (int g = 0; g < 2; ++g) {
    const float invl = 1.f / l4[g][0];
    bf16* yp = yb + (rowbase + gq0[g] + l15) * 1024 + cb + quad * 4;
#pragma unroll
    for (int dt = 0; dt < 4; ++dt) {
      ushort4 pk;
      pk.x = f2bf_bits(o[g][dt][0] * invl);
      pk.y = f2bf_bits(o[g][dt][1] * invl);
      pk.z = f2bf_bits(o[g][dt][2] * invl);
      pk.w = f2bf_bits(o[g][dt][3] * invl);
      *reinterpret_cast<ushort4*>(&yp[dt * 16]) = pk;
    }
  }
}

// ---------------------------------------------------------------------- launch
extern "C" void kernel_launch(void* const* d_in, const int* in_sizes, int n_in,
                              void* d_out, int out_size, void* d_ws, size_t ws_size,
                              hipStream_t stream) {
  const float* x = (const float*)d_in[0];
  const float* Wq = (const float*)d_in[1];
  const float* Wk = (const float*)d_in[2];
  const float* Wv = (const float*)d_in[3];
  const float* Wp = (const float*)d_in[4];
  float* out = (float*)d_out;

  const size_t MB = 1024 * 1024;
  char* ws = (char*)d_ws;
  bf16* xb = (bf16*)(ws);             // 16 MB; reused as yb after QKV
  bf16* qb = (bf16*)(ws + 16 * MB);   // 16 MB
  bf16* kb = (bf16*)(ws + 32 * MB);   // 16 MB
  bf16* vtb = (bf16*)(ws + 48 * MB);  // 16 MB, V transposed [bh][d][t]
  bf16* wqb = (bf16*)(ws + 64 * MB);  // 2 MB each
  bf16* wkb = (bf16*)(ws + 66 * MB);
  bf16* wvb = (bf16*)(ws + 68 * MB);
  bf16* wpb = (bf16*)(ws + 70 * MB);
  bf16* yb = xb;

  cvt_all<<<12288, 256, 0, stream>>>(x, Wq, Wk, Wv, Wp, xb, wqb, wkb, wvb, wpb);
  gemm_qkv<<<dim3(8, 64, 3), 256, 0, stream>>>(xb, wqb, wkb, wvb, qb, kb, vtb);
  attn<<<dim3(64, 16), 256, 0, stream>>>(qb, kb, vtb, yb);
  gemm_proj<<<dim3(8, 64), 256, 0, stream>>>(yb, wpb, out);
}